// Round 9
// baseline (234.098 us; speedup 1.0000x reference)
//
#include <hip/hip_runtime.h>
#include <math.h>

#define HDIM 4096
#define NBLK 128
#define RNK  4
#define TOPK 3

typedef float f4 __attribute__((ext_vector_type(4)));
typedef float f2 __attribute__((ext_vector_type(2)));
typedef _Float16 h8 __attribute__((ext_vector_type(8)));

// ---- preprocessing (VERBATIM round 3/7, passed): A fp32 -> fp16 copy ----
__global__ __launch_bounds__(256) void convert_A(
    const float* __restrict__ A, _Float16* __restrict__ Ah)
{
    int i = blockIdx.x * 256 + threadIdx.x;            // half8 index
    const f4* src = reinterpret_cast<const f4*>(A);
    f4 a0 = __builtin_nontemporal_load(src + 2 * i);
    f4 a1 = __builtin_nontemporal_load(src + 2 * i + 1);
    h8 r;
    r[0] = (_Float16)a0.x; r[1] = (_Float16)a0.y;
    r[2] = (_Float16)a0.z; r[3] = (_Float16)a0.w;
    r[4] = (_Float16)a1.x; r[5] = (_Float16)a1.y;
    r[6] = (_Float16)a1.z; r[7] = (_Float16)a1.w;
    reinterpret_cast<h8*>(Ah)[i] = r;
}

// One workgroup (256 threads) per token. ARITHMETIC IS BIT-IDENTICAL TO THE
// PASSING ROUND-7 KERNEL: same data layouts, same expressions, same
// accumulation orders, same reduction trees, same fp16 A table.
// Schedule-only changes (value-preserving):
//  - phase 1: all 8 x/temb loads issued before the Wp FMA chain (same
//    k-ascending accumulation -> same bits; 8 loads in flight)
//  - z loop: j-outer / kk-inner interleave -> 3 independent A load streams
//    in flight; h read from LDS once per j (24 -> 8 LDS reads); each
//    zp[kk][r] keeps its exact r7 expression and j-ascending order.
template<bool FP16A>
__global__ __launch_bounds__(256) void npl_fused(
    const float* __restrict__ x,
    const int*   __restrict__ task_ids,
    const float* __restrict__ task_emb,
    const float* __restrict__ Wp,
    const float* __restrict__ bp,
    const float* __restrict__ centers,
    const float* __restrict__ A,
    const _Float16* __restrict__ Ah,
    const float* __restrict__ Bm,
    const float* __restrict__ scale_p,
    float* __restrict__ out,
    int S_per_batch)
{
    __shared__ float h_lds[HDIM];
    __shared__ float redc[4][4];
    __shared__ float redz[4][12];

    const int tid  = threadIdx.x;
    const int wid  = tid >> 6;
    const int lane = tid & 63;
    const int token = blockIdx.x;
    const int b = token / S_per_batch;
    const int task = task_ids[b];

    const float* xrow = x + (size_t)token * HDIM;
    const float* trow = task_emb + (size_t)task * HDIM;
    float*       orow = out + (size_t)token * HDIM;

    const f4* xr4 = reinterpret_cast<const f4*>(xrow);
    const f4* tr4 = reinterpret_cast<const f4*>(trow);
    f4*       or4 = reinterpret_cast<f4*>(orow);

    // ---- phase 1: hoisted loads, then r7's exact FMA chain ----
    f4 xv[4], tv[4];
#pragma unroll
    for (int k = 0; k < 4; ++k) {
        int i4 = tid + k * 256;
        xv[k] = __builtin_nontemporal_load(xr4 + i4);
        tv[k] = tr4[i4];
    }
    float c0 = 0.f, c1 = 0.f, c2 = 0.f;
#pragma unroll
    for (int k = 0; k < 4; ++k) {
        int i4 = tid + k * 256;
        f4 hh = xv[k] + tv[k];
        reinterpret_cast<f4*>(h_lds)[i4] = hh;
        int e = i4 * 4;
        const float* wrow = Wp + (size_t)e * 3;   // 12 consecutive floats
        c0 += hh.x * wrow[0];  c1 += hh.x * wrow[1];  c2 += hh.x * wrow[2];
        c0 += hh.y * wrow[3];  c1 += hh.y * wrow[4];  c2 += hh.y * wrow[5];
        c0 += hh.z * wrow[6];  c1 += hh.z * wrow[7];  c2 += hh.z * wrow[8];
        c0 += hh.w * wrow[9];  c1 += hh.w * wrow[10]; c2 += hh.w * wrow[11];
    }
#pragma unroll
    for (int off = 32; off; off >>= 1) {
        c0 += __shfl_down(c0, off);
        c1 += __shfl_down(c1, off);
        c2 += __shfl_down(c2, off);
    }
    if (lane == 0) { redc[wid][0] = c0; redc[wid][1] = c1; redc[wid][2] = c2; }
    __syncthreads();   // barrier 1 of 2

    // ---- coords finalize: every thread, r3's exact left-assoc sum ----
    c0 = redc[0][0] + redc[1][0] + redc[2][0] + redc[3][0] + bp[0];
    c1 = redc[0][1] + redc[1][1] + redc[2][1] + redc[3][1] + bp[1];
    c2 = redc[0][2] + redc[1][2] + redc[2][2] + redc[3][2] + bp[2];

    // ---- scores for blocks `lane` and `lane+64` (r3 expression) ----
    float dx = c0 - centers[lane * 3 + 0];
    float dy = c1 - centers[lane * 3 + 1];
    float dz = c2 - centers[lane * 3 + 2];
    float v1 = -0.5f * (dx * dx + dy * dy + dz * dz);
    dx = c0 - centers[(lane + 64) * 3 + 0];
    dy = c1 - centers[(lane + 64) * 3 + 1];
    dz = c2 - centers[(lane + 64) * 3 + 2];
    float v2 = -0.5f * (dx * dx + dy * dy + dz * dz);

    // ---- top-3 (r3 loop verbatim, redundant on every wave) ----
    float tv0, tv1, tv2; int n0, n1, n2;
#pragma unroll
    for (int kk = 0; kk < TOPK; ++kk) {
        float v = v1; int idx = lane;
        if (v2 > v || (v2 == v && (lane + 64) < idx)) { v = v2; idx = lane + 64; }
#pragma unroll
        for (int off = 32; off; off >>= 1) {
            float ov = __shfl_down(v, off);
            int   oi = __shfl_down(idx, off);
            if (ov > v || (ov == v && oi < idx)) { v = ov; idx = oi; }
        }
        idx = __shfl(idx, 0);
        v   = __shfl(v, 0);
        if (kk == 0)      { tv0 = v; n0 = idx; }
        else if (kk == 1) { tv1 = v; n1 = idx; }
        else              { tv2 = v; n2 = idx; }
        if (idx == lane)      v1 = -3.0e38f;
        if (idx == lane + 64) v2 = -3.0e38f;
    }

    // ---- gates (r3 op sequence) ----
    float m  = tv0;
    float e0 = 1.0f;
    float e1 = expf(tv1 - m);
    float e2 = expf(tv2 - m);
    float inv = 1.0f / (e0 + e1 + e2);
    float s = scale_p[0];
    float g0 = e0 * inv * s;
    float g1 = e1 * inv * s;
    float g2 = e2 * inv * s;

    // ---- z_k = h @ A[n_k]: r7 layout & expressions, kk-interleaved loads ----
    float zp[TOPK][RNK];
#pragma unroll
    for (int kk = 0; kk < TOPK; ++kk)
#pragma unroll
        for (int r = 0; r < RNK; ++r) zp[kk][r] = 0.f;

    if (FP16A) {
        const h8* A0 = reinterpret_cast<const h8*>(Ah + (size_t)n0 * HDIM * RNK);
        const h8* A1 = reinterpret_cast<const h8*>(Ah + (size_t)n1 * HDIM * RNK);
        const h8* A2 = reinterpret_cast<const h8*>(Ah + (size_t)n2 * HDIM * RNK);
#pragma unroll
        for (int j = 0; j < 8; ++j) {
            int idx = tid + j * 256;
            h8 a0 = A0[idx];
            h8 a1 = A1[idx];
            h8 a2 = A2[idx];
            f2 hv = reinterpret_cast<const f2*>(h_lds)[idx];
            zp[0][0] += hv.x * (float)a0[0] + hv.y * (float)a0[4];
            zp[0][1] += hv.x * (float)a0[1] + hv.y * (float)a0[5];
            zp[0][2] += hv.x * (float)a0[2] + hv.y * (float)a0[6];
            zp[0][3] += hv.x * (float)a0[3] + hv.y * (float)a0[7];
            zp[1][0] += hv.x * (float)a1[0] + hv.y * (float)a1[4];
            zp[1][1] += hv.x * (float)a1[1] + hv.y * (float)a1[5];
            zp[1][2] += hv.x * (float)a1[2] + hv.y * (float)a1[6];
            zp[1][3] += hv.x * (float)a1[3] + hv.y * (float)a1[7];
            zp[2][0] += hv.x * (float)a2[0] + hv.y * (float)a2[4];
            zp[2][1] += hv.x * (float)a2[1] + hv.y * (float)a2[5];
            zp[2][2] += hv.x * (float)a2[2] + hv.y * (float)a2[6];
            zp[2][3] += hv.x * (float)a2[3] + hv.y * (float)a2[7];
        }
    } else {
#pragma unroll
        for (int kk = 0; kk < TOPK; ++kk) {
            int n = (kk == 0) ? n0 : (kk == 1) ? n1 : n2;
            const f4* Arow = reinterpret_cast<const f4*>(A + (size_t)n * HDIM * RNK);
#pragma unroll 4
            for (int k = 0; k < 16; ++k) {
                int i = tid + k * 256;
                f4 a = Arow[i];
                float hv = h_lds[i];
                zp[kk][0] += hv * a.x;
                zp[kk][1] += hv * a.y;
                zp[kk][2] += hv * a.z;
                zp[kk][3] += hv * a.w;
            }
        }
    }
#pragma unroll
    for (int off = 32; off; off >>= 1) {
#pragma unroll
        for (int kk = 0; kk < TOPK; ++kk)
#pragma unroll
            for (int r = 0; r < RNK; ++r)
                zp[kk][r] += __shfl_down(zp[kk][r], off);
    }
    if (lane == 0) {
#pragma unroll
        for (int kk = 0; kk < TOPK; ++kk)
#pragma unroll
            for (int r = 0; r < RNK; ++r)
                redz[wid][kk * RNK + r] = zp[kk][r];
    }
    __syncthreads();   // barrier 2 of 2

    // ---- zf: every thread, left-assoc cross-wave sum (r7 pattern) ----
    float zf_[12];
#pragma unroll
    for (int t = 0; t < 12; ++t)
        zf_[t] = redz[0][t] + redz[1][t] + redz[2][t] + redz[3][t];

    // ---- out = x + delta (delta recomputed in-register, r7 expression) ----
#pragma unroll
    for (int k = 0; k < 4; ++k) {
        int i4 = tid + k * 256;
        int e = i4 * 4;          // all 4 elements in the same 32-block
        int bb = e >> 5;
        f4 o = xv[k];
        int kk = (bb == n0) ? 0 : (bb == n1) ? 1 : (bb == n2) ? 2 : -1;
        if (kk >= 0) {
            int nn = (kk == 0) ? n0 : (kk == 1) ? n1 : n2;
            float za = (kk == 0) ? zf_[0] : (kk == 1) ? zf_[4] : zf_[8];
            float zb = (kk == 0) ? zf_[1] : (kk == 1) ? zf_[5] : zf_[9];
            float zc = (kk == 0) ? zf_[2] : (kk == 1) ? zf_[6] : zf_[10];
            float zd = (kk == 0) ? zf_[3] : (kk == 1) ? zf_[7] : zf_[11];
            float gg = (kk == 0) ? g0 : (kk == 1) ? g1 : g2;
            const float* bm = Bm + (size_t)nn * 128;
            int c = e & 31;
            float d0 = za * bm[c + 0] + zb * bm[32 + c + 0] + zc * bm[64 + c + 0] + zd * bm[96 + c + 0];
            float d1 = za * bm[c + 1] + zb * bm[32 + c + 1] + zc * bm[64 + c + 1] + zd * bm[96 + c + 1];
            float d2 = za * bm[c + 2] + zb * bm[32 + c + 2] + zc * bm[64 + c + 2] + zd * bm[96 + c + 2];
            float d3 = za * bm[c + 3] + zb * bm[32 + c + 3] + zc * bm[64 + c + 3] + zd * bm[96 + c + 3];
            o.x += d0 * gg;
            o.y += d1 * gg;
            o.z += d2 * gg;
            o.w += d3 * gg;
        }
        __builtin_nontemporal_store(o, or4 + i4);
    }
}

extern "C" void kernel_launch(void* const* d_in, const int* in_sizes, int n_in,
                              void* d_out, int out_size, void* d_ws, size_t ws_size,
                              hipStream_t stream) {
    const float* x        = (const float*)d_in[0];
    const int*   task_ids = (const int*)  d_in[1];
    const float* task_emb = (const float*)d_in[2];
    const float* Wp       = (const float*)d_in[3];
    const float* bp       = (const float*)d_in[4];
    const float* centers  = (const float*)d_in[5];
    const float* A        = (const float*)d_in[6];
    const float* Bm       = (const float*)d_in[7];
    const float* scale    = (const float*)d_in[8];

    int tokens = in_sizes[0] / HDIM;   // B*S
    int B      = in_sizes[1];
    int S      = tokens / B;

    const size_t A_elems = (size_t)NBLK * HDIM * RNK;        // 2,097,152
    const size_t need    = A_elems * sizeof(_Float16);       // 4 MiB

    if (ws_size >= need) {
        _Float16* Ah = (_Float16*)d_ws;
        convert_A<<<dim3((int)(A_elems / 8 / 256)), dim3(256), 0, stream>>>(A, Ah);
        npl_fused<true><<<dim3(tokens), dim3(256), 0, stream>>>(
            x, task_ids, task_emb, Wp, bp, centers, A, Ah, Bm, scale,
            (float*)d_out, S);
    } else {
        npl_fused<false><<<dim3(tokens), dim3(256), 0, stream>>>(
            x, task_ids, task_emb, Wp, bp, centers, A, (const _Float16*)d_ws, Bm, scale,
            (float*)d_out, S);
    }
}

// Round 10
// 196.676 us; speedup vs baseline: 1.1903x; 1.1903x over previous
//
#include <hip/hip_runtime.h>
#include <math.h>

#define HDIM 4096
#define NBLK 128
#define RNK  4
#define TOPK 3

typedef float f4 __attribute__((ext_vector_type(4)));
typedef float f2 __attribute__((ext_vector_type(2)));
typedef unsigned int u32;
typedef u32 u4 __attribute__((ext_vector_type(4)));

// fp8 e4m3 (OCP on gfx950) pack/unpack via native ops
__device__ __forceinline__ u32 pk_fp8(f4 v) {
    u32 w = (u32)__builtin_amdgcn_cvt_pk_fp8_f32(v.x, v.y, 0, false);
    w = (u32)__builtin_amdgcn_cvt_pk_fp8_f32(v.z, v.w, (int)w, true);
    return w;
}
__device__ __forceinline__ f2 upk_fp8(u32 w, bool hi) {
    typedef float vf2 __attribute__((ext_vector_type(2)));
    vf2 r = hi ? __builtin_amdgcn_cvt_pk_f32_fp8((int)w, true)
               : __builtin_amdgcn_cvt_pk_f32_fp8((int)w, false);
    f2 o; o.x = r.x; o.y = r.y; return o;
}

// ---- preprocessing: A [NB][H][RNK] fp32 -> fp8 e4m3, SAME element order ----
// dword d = row i (4 ranks); u4 = 4 consecutive rows. 2 MiB total (half an
// XCD L2) for the ~0.75 GB of z-phase re-reads.
__global__ __launch_bounds__(256) void convert_A8(
    const float* __restrict__ A, u32* __restrict__ Af8)
{
    int d = blockIdx.x * 256 + threadIdx.x;            // u4 index 0..131071
    const f4* src = reinterpret_cast<const f4*>(A) + 4 * (size_t)d;
    f4 r0 = __builtin_nontemporal_load(src + 0);
    f4 r1 = __builtin_nontemporal_load(src + 1);
    f4 r2 = __builtin_nontemporal_load(src + 2);
    f4 r3 = __builtin_nontemporal_load(src + 3);
    u4 o;
    o.x = pk_fp8(r0); o.y = pk_fp8(r1); o.z = pk_fp8(r2); o.w = pk_fp8(r3);
    reinterpret_cast<u4*>(Af8)[d] = o;
}

// One workgroup (256 threads) per token. Coords/top-k/gates/scatter are
// VERBATIM round 7 (bit-identical selection, PASSED twice). Only the z-phase
// A-operand changes: fp8 e4m3 table (2 MiB, L2-resident), decoded in-loop
// with v_cvt_pk_f32_fp8, FMA vs h (fp32, LDS). z summation-order changes are
// smooth error only (selection unaffected).
__global__ __launch_bounds__(256) void npl_fused(
    const float* __restrict__ x,
    const int*   __restrict__ task_ids,
    const float* __restrict__ task_emb,
    const float* __restrict__ Wp,
    const float* __restrict__ bp,
    const float* __restrict__ centers,
    const u32*   __restrict__ Af8,
    const float* __restrict__ Bm,
    const float* __restrict__ scale_p,
    float* __restrict__ out,
    int S_per_batch)
{
    __shared__ float h_lds[HDIM];
    __shared__ float redc[4][4];
    __shared__ float redz[4][12];

    const int tid  = threadIdx.x;
    const int wid  = tid >> 6;
    const int lane = tid & 63;
    const int token = blockIdx.x;
    const int b = token / S_per_batch;
    const int task = task_ids[b];

    const float* xrow = x + (size_t)token * HDIM;
    const float* trow = task_emb + (size_t)task * HDIM;
    float*       orow = out + (size_t)token * HDIM;

    const f4* xr4 = reinterpret_cast<const f4*>(xrow);
    const f4* tr4 = reinterpret_cast<const f4*>(trow);
    f4*       or4 = reinterpret_cast<f4*>(orow);

    // ---- phase 1 (verbatim r7): stage h to LDS, x in regs, coords partials ----
    f4 xv[4];
    float c0 = 0.f, c1 = 0.f, c2 = 0.f;
#pragma unroll
    for (int k = 0; k < 4; ++k) {
        int i4 = tid + k * 256;
        f4 xx = __builtin_nontemporal_load(xr4 + i4);
        f4 tt = tr4[i4];
        xv[k] = xx;
        f4 hh = xx + tt;
        reinterpret_cast<f4*>(h_lds)[i4] = hh;
        int e = i4 * 4;
        const float* wrow = Wp + (size_t)e * 3;   // 12 consecutive floats
        c0 += hh.x * wrow[0];  c1 += hh.x * wrow[1];  c2 += hh.x * wrow[2];
        c0 += hh.y * wrow[3];  c1 += hh.y * wrow[4];  c2 += hh.y * wrow[5];
        c0 += hh.z * wrow[6];  c1 += hh.z * wrow[7];  c2 += hh.z * wrow[8];
        c0 += hh.w * wrow[9];  c1 += hh.w * wrow[10]; c2 += hh.w * wrow[11];
    }
#pragma unroll
    for (int off = 32; off; off >>= 1) {
        c0 += __shfl_down(c0, off);
        c1 += __shfl_down(c1, off);
        c2 += __shfl_down(c2, off);
    }
    if (lane == 0) { redc[wid][0] = c0; redc[wid][1] = c1; redc[wid][2] = c2; }
    __syncthreads();   // barrier 1 of 2

    // ---- coords finalize: every thread, exact left-assoc sum (r7) ----
    c0 = redc[0][0] + redc[1][0] + redc[2][0] + redc[3][0] + bp[0];
    c1 = redc[0][1] + redc[1][1] + redc[2][1] + redc[3][1] + bp[1];
    c2 = redc[0][2] + redc[1][2] + redc[2][2] + redc[3][2] + bp[2];

    // ---- scores for blocks `lane` and `lane+64` (r7 expression) ----
    float dx = c0 - centers[lane * 3 + 0];
    float dy = c1 - centers[lane * 3 + 1];
    float dz = c2 - centers[lane * 3 + 2];
    float v1 = -0.5f * (dx * dx + dy * dy + dz * dz);
    dx = c0 - centers[(lane + 64) * 3 + 0];
    dy = c1 - centers[(lane + 64) * 3 + 1];
    dz = c2 - centers[(lane + 64) * 3 + 2];
    float v2 = -0.5f * (dx * dx + dy * dy + dz * dz);

    // ---- top-3 (r7 loop verbatim, redundant on every wave) ----
    float tv0, tv1, tv2; int n0, n1, n2;
#pragma unroll
    for (int kk = 0; kk < TOPK; ++kk) {
        float v = v1; int idx = lane;
        if (v2 > v || (v2 == v && (lane + 64) < idx)) { v = v2; idx = lane + 64; }
#pragma unroll
        for (int off = 32; off; off >>= 1) {
            float ov = __shfl_down(v, off);
            int   oi = __shfl_down(idx, off);
            if (ov > v || (ov == v && oi < idx)) { v = ov; idx = oi; }
        }
        idx = __shfl(idx, 0);
        v   = __shfl(v, 0);
        if (kk == 0)      { tv0 = v; n0 = idx; }
        else if (kk == 1) { tv1 = v; n1 = idx; }
        else              { tv2 = v; n2 = idx; }
        if (idx == lane)      v1 = -3.0e38f;
        if (idx == lane + 64) v2 = -3.0e38f;
    }

    // ---- gates (r7 op sequence) ----
    float m  = tv0;
    float e0 = 1.0f;
    float e1 = expf(tv1 - m);
    float e2 = expf(tv2 - m);
    float inv = 1.0f / (e0 + e1 + e2);
    float s = scale_p[0];
    float g0 = e0 * inv * s;
    float g1 = e1 * inv * s;
    float g2 = e2 * inv * s;

    // ---- z_k = h @ A[n_k]: fp8 table, in-loop decode, h fp32 from LDS ----
    float zp[TOPK][RNK];
#pragma unroll
    for (int kk = 0; kk < TOPK; ++kk)
#pragma unroll
        for (int r = 0; r < RNK; ++r) zp[kk][r] = 0.f;

#pragma unroll
    for (int kk = 0; kk < TOPK; ++kk) {
        int n = (kk == 0) ? n0 : (kk == 1) ? n1 : n2;
        const u4* Ab = reinterpret_cast<const u4*>(Af8) + (size_t)n * 1024;
#pragma unroll
        for (int k = 0; k < 4; ++k) {
            int idx = tid + k * 256;
            u4 q = Ab[idx];                                   // rows 4idx..4idx+3
            f4 hv = reinterpret_cast<const f4*>(h_lds)[idx];
            f2 p;
            p = upk_fp8(q.x, false); zp[kk][0] += hv.x * p.x; zp[kk][1] += hv.x * p.y;
            p = upk_fp8(q.x, true);  zp[kk][2] += hv.x * p.x; zp[kk][3] += hv.x * p.y;
            p = upk_fp8(q.y, false); zp[kk][0] += hv.y * p.x; zp[kk][1] += hv.y * p.y;
            p = upk_fp8(q.y, true);  zp[kk][2] += hv.y * p.x; zp[kk][3] += hv.y * p.y;
            p = upk_fp8(q.z, false); zp[kk][0] += hv.z * p.x; zp[kk][1] += hv.z * p.y;
            p = upk_fp8(q.z, true);  zp[kk][2] += hv.z * p.x; zp[kk][3] += hv.z * p.y;
            p = upk_fp8(q.w, false); zp[kk][0] += hv.w * p.x; zp[kk][1] += hv.w * p.y;
            p = upk_fp8(q.w, true);  zp[kk][2] += hv.w * p.x; zp[kk][3] += hv.w * p.y;
        }
    }
#pragma unroll
    for (int off = 32; off; off >>= 1) {
#pragma unroll
        for (int kk = 0; kk < TOPK; ++kk)
#pragma unroll
            for (int r = 0; r < RNK; ++r)
                zp[kk][r] += __shfl_down(zp[kk][r], off);
    }
    if (lane == 0) {
#pragma unroll
        for (int kk = 0; kk < TOPK; ++kk)
#pragma unroll
            for (int r = 0; r < RNK; ++r)
                redz[wid][kk * RNK + r] = zp[kk][r];
    }
    __syncthreads();   // barrier 2 of 2

    // ---- zf: every thread, left-assoc cross-wave sum (r7) ----
    float zf_[12];
#pragma unroll
    for (int t = 0; t < 12; ++t)
        zf_[t] = redz[0][t] + redz[1][t] + redz[2][t] + redz[3][t];

    // ---- out = x + delta (delta recomputed in-register, r7 expression) ----
#pragma unroll
    for (int k = 0; k < 4; ++k) {
        int i4 = tid + k * 256;
        int e = i4 * 4;          // all 4 elements in the same 32-block
        int bb = e >> 5;
        f4 o = xv[k];
        int kk = (bb == n0) ? 0 : (bb == n1) ? 1 : (bb == n2) ? 2 : -1;
        if (kk >= 0) {
            int nn = (kk == 0) ? n0 : (kk == 1) ? n1 : n2;
            float za = (kk == 0) ? zf_[0] : (kk == 1) ? zf_[4] : zf_[8];
            float zb = (kk == 0) ? zf_[1] : (kk == 1) ? zf_[5] : zf_[9];
            float zc = (kk == 0) ? zf_[2] : (kk == 1) ? zf_[6] : zf_[10];
            float zd = (kk == 0) ? zf_[3] : (kk == 1) ? zf_[7] : zf_[11];
            float gg = (kk == 0) ? g0 : (kk == 1) ? g1 : g2;
            const float* bm = Bm + (size_t)nn * 128;
            int c = e & 31;
            float d0 = za * bm[c + 0] + zb * bm[32 + c + 0] + zc * bm[64 + c + 0] + zd * bm[96 + c + 0];
            float d1 = za * bm[c + 1] + zb * bm[32 + c + 1] + zc * bm[64 + c + 1] + zd * bm[96 + c + 1];
            float d2 = za * bm[c + 2] + zb * bm[32 + c + 2] + zc * bm[64 + c + 2] + zd * bm[96 + c + 2];
            float d3 = za * bm[c + 3] + zb * bm[32 + c + 3] + zc * bm[64 + c + 3] + zd * bm[96 + c + 3];
            o.x += d0 * gg;
            o.y += d1 * gg;
            o.z += d2 * gg;
            o.w += d3 * gg;
        }
        __builtin_nontemporal_store(o, or4 + i4);
    }
}

extern "C" void kernel_launch(void* const* d_in, const int* in_sizes, int n_in,
                              void* d_out, int out_size, void* d_ws, size_t ws_size,
                              hipStream_t stream) {
    const float* x        = (const float*)d_in[0];
    const int*   task_ids = (const int*)  d_in[1];
    const float* task_emb = (const float*)d_in[2];
    const float* Wp       = (const float*)d_in[3];
    const float* bp       = (const float*)d_in[4];
    const float* centers  = (const float*)d_in[5];
    const float* A        = (const float*)d_in[6];
    const float* Bm       = (const float*)d_in[7];
    const float* scale    = (const float*)d_in[8];

    int tokens = in_sizes[0] / HDIM;   // B*S
    int B      = in_sizes[1];
    int S      = tokens / B;

    u32* Af8 = (u32*)d_ws;             // 2 MiB (ws >= 4 MiB proven in rounds 3-9)

    const int n_u4 = NBLK * HDIM * RNK / 16;     // 131072 u4s
    convert_A8<<<dim3(n_u4 / 256), dim3(256), 0, stream>>>(A, Af8);
    npl_fused<<<dim3(tokens), dim3(256), 0, stream>>>(
        x, task_ids, task_emb, Wp, bp, centers, Af8, Bm, scale,
        (float*)d_out, S);
}